// Round 4
// baseline (98.103 us; speedup 1.0000x reference)
//
#include <hip/hip_runtime.h>

#define TT 65536          // total tokens = 8 * 8192
#define HDIM 512
#define NE 4
#define SEQL 8192
#define TPB 64            // tokens per block
#define NBLK (TT / TPB)   // 1024 blocks
#define BPB (SEQL / TPB)  // 128 blocks per batch
#define TPW 16            // tokens per wave
#define EPS 1e-3f         // 500x the fp32 tree-reduction error bound (~2e-6)

// Wave-per-token, 2 tokens interleaved per iteration (2x ILP on the
// dependent shuffle chain, which R3 showed is the limiter — fp64->fp32
// compute changed nothing). fp32 logits; one combined rare fp64 fallback
// per pair preserves exact np-float64 top-k ordering.
__global__ __launch_bounds__(256, 4) void moe_gate_main(
    const float* __restrict__ x, const float* __restrict__ w,
    float* __restrict__ out, float* __restrict__ ws)
{
  const int lane = threadIdx.x & 63;
  const int wave = threadIdx.x >> 6;
  const int b0 = lane & 1;
  const int b1 = (lane >> 1) & 1;

  // fp32 weight fragments: w[e][4*lane..+3], w[e][256+4*lane..+3]  (32 VGPRs)
  float4 wA[NE], wB[NE];
#pragma unroll
  for (int e = 0; e < NE; ++e) {
    wA[e] = *(const float4*)(w + e * HDIM + 4 * lane);
    wB[e] = *(const float4*)(w + e * HDIM + 256 + 4 * lane);
  }

  float ssum[NE] = {0.f, 0.f, 0.f, 0.f};
  float cnt[NE]  = {0.f, 0.f, 0.f, 0.f};

  const int t0 = blockIdx.x * TPB + wave * TPW;
  const float4* xp = (const float4*)x;
  const size_t base = (size_t)t0 * (HDIM / 4);

  // current pair + prefetched next pair (4 tokens x 8 VGPRs)
  float4 xA0 = xp[base + lane],       xB0 = xp[base + 64 + lane];
  float4 xA1 = xp[base + 128 + lane], xB1 = xp[base + 192 + lane];

  for (int i = 0; i < TPW; i += 2) {
    float4 nA0, nB0, nA1, nB1;
    if (i + 2 < TPW) {
      const size_t nb = base + (size_t)(i + 2) * (HDIM / 4);
      nA0 = xp[nb + lane];       nB0 = xp[nb + 64 + lane];
      nA1 = xp[nb + 128 + lane]; nB1 = xp[nb + 192 + lane];
    }

    // per-lane fp32 partials for both tokens
    float pe0[NE], pe1[NE];
#pragma unroll
    for (int e = 0; e < NE; ++e) {
      float s = xA0.x * wA[e].x;
      s = fmaf(xA0.y, wA[e].y, s); s = fmaf(xA0.z, wA[e].z, s);
      s = fmaf(xA0.w, wA[e].w, s); s = fmaf(xB0.x, wB[e].x, s);
      s = fmaf(xB0.y, wB[e].y, s); s = fmaf(xB0.z, wB[e].z, s);
      s = fmaf(xB0.w, wB[e].w, s);
      pe0[e] = s;
      float t = xA1.x * wA[e].x;
      t = fmaf(xA1.y, wA[e].y, t); t = fmaf(xA1.z, wA[e].z, t);
      t = fmaf(xA1.w, wA[e].w, t); t = fmaf(xB1.x, wB[e].x, t);
      t = fmaf(xB1.y, wB[e].y, t); t = fmaf(xB1.z, wB[e].z, t);
      t = fmaf(xB1.w, wB[e].w, t);
      pe1[e] = t;
    }

    // two independent shuffle chains in one basic block -> interleaved issue
    float acc0[NE], acc1[NE];
#define CHAIN(pe, acc)                                                         \
    { const float s0 = (b0 ? pe[2] : pe[0]) + __shfl_xor(b0 ? pe[0] : pe[2], 1, 64); \
      const float s1 = (b0 ? pe[3] : pe[1]) + __shfl_xor(b0 ? pe[1] : pe[3], 1, 64); \
      float v = (b1 ? s1 : s0) + __shfl_xor(b1 ? s0 : s1, 2, 64);              \
      v += __shfl_xor(v, 4, 64);  v += __shfl_xor(v, 8, 64);                   \
      v += __shfl_xor(v, 16, 64); v += __shfl_xor(v, 32, 64);                  \
      const float t2 = __shfl_xor(v, 1, 64);                                   \
      const float t1 = __shfl_xor(v, 2, 64);                                   \
      const float t3 = __shfl_xor(v, 3, 64);                                   \
      acc[0] = b0 ? (b1 ? t3 : t2) : (b1 ? t1 : v);                            \
      acc[1] = b0 ? (b1 ? t2 : t3) : (b1 ? v  : t1);                           \
      acc[2] = b0 ? (b1 ? t1 : v)  : (b1 ? t3 : t2);                           \
      acc[3] = b0 ? (b1 ? v  : t1) : (b1 ? t2 : t3); }
    CHAIN(pe0, acc0)
    CHAIN(pe1, acc1)
#undef CHAIN

    // top-k both tokens; strict '>' ascending = lowest-index tie-break
    int i00 = 0; float v00 = acc0[0];
    int i10 = 0; float v10 = acc1[0];
#pragma unroll
    for (int e = 1; e < NE; ++e) {
      if (acc0[e] > v00) { v00 = acc0[e]; i00 = e; }
      if (acc1[e] > v10) { v10 = acc1[e]; i10 = e; }
    }
    int i01 = -1; float v01 = -3.4e38f;
    int i11 = -1; float v11 = -3.4e38f;
#pragma unroll
    for (int e = 0; e < NE; ++e) {
      if (e != i00 && acc0[e] > v01) { v01 = acc0[e]; i01 = e; }
      if (e != i10 && acc1[e] > v11) { v11 = acc1[e]; i11 = e; }
    }
    float v02 = -3.4e38f, v12 = -3.4e38f;
#pragma unroll
    for (int e = 0; e < NE; ++e) {
      if (e != i00 && e != i01 && acc0[e] > v02) v02 = acc0[e];
      if (e != i10 && e != i11 && acc1[e] > v12) v12 = acc1[e];
    }

    // combined near-tie check (wave-uniform; butterfly values bitwise-identical)
    const int risky = ((v00 - v01) < EPS) | ((v01 - v02) < EPS) |
                      ((v10 - v11) < EPS) | ((v11 - v12) < EPS);
    if (__builtin_amdgcn_readfirstlane(risky)) {
      // rare fp64 recompute of both tokens, expert-serial (low reg pressure)
      const float xe0[8] = {xA0.x, xA0.y, xA0.z, xA0.w, xB0.x, xB0.y, xB0.z, xB0.w};
      const float xe1[8] = {xA1.x, xA1.y, xA1.z, xA1.w, xB1.x, xB1.y, xB1.z, xB1.w};
      double ad0[NE], ad1[NE];
#pragma unroll
      for (int e = 0; e < NE; ++e) {
        const float we[8] = {wA[e].x, wA[e].y, wA[e].z, wA[e].w,
                             wB[e].x, wB[e].y, wB[e].z, wB[e].w};
        double a = 0.0, b = 0.0;
#pragma unroll
        for (int j = 0; j < 8; ++j) {
          a += (double)xe0[j] * (double)we[j];
          b += (double)xe1[j] * (double)we[j];
        }
        // full butterfly per expert (rare path; depth is irrelevant here)
#pragma unroll
        for (int m = 1; m < 64; m <<= 1) {
          a += __shfl_xor(a, m, 64);
          b += __shfl_xor(b, m, 64);
        }
        ad0[e] = a; ad1[e] = b;
      }
      i00 = 0; double w00 = ad0[0]; i10 = 0; double w10 = ad1[0];
#pragma unroll
      for (int e = 1; e < NE; ++e) {
        if (ad0[e] > w00) { w00 = ad0[e]; i00 = e; }
        if (ad1[e] > w10) { w10 = ad1[e]; i10 = e; }
      }
      i01 = -1; double w01 = -1.0e300; i11 = -1; double w11 = -1.0e300;
#pragma unroll
      for (int e = 0; e < NE; ++e) {
        if (e != i00 && ad0[e] > w01) { w01 = ad0[e]; i01 = e; }
        if (e != i10 && ad1[e] > w11) { w11 = ad1[e]; i11 = e; }
      }
#pragma unroll
      for (int e = 0; e < NE; ++e) { acc0[e] = (float)ad0[e]; acc1[e] = (float)ad1[e]; }
      v00 = (float)w00; v10 = (float)w10;
    }

    // softmax both tokens (fp32)
    float u0[NE], u1[NE]; float ps0 = 0.f, ps1 = 0.f;
#pragma unroll
    for (int e = 0; e < NE; ++e) {
      u0[e] = __expf(acc0[e] - v00); ps0 += u0[e];
      u1[e] = __expf(acc1[e] - v10); ps1 += u1[e];
    }
    const float inv0 = 1.0f / ps0, inv1 = 1.0f / ps1;
#pragma unroll
    for (int e = 0; e < NE; ++e) {
      ssum[e] += u0[e] * inv0 + u1[e] * inv1;
      cnt[e] += ((e == i00) ? 1.f : 0.f) + ((e == i01) ? 1.f : 0.f)
              + ((e == i10) ? 1.f : 0.f) + ((e == i11) ? 1.f : 0.f);
    }

    const float ua0 = (i00 == 0) ? u0[0] : (i00 == 1) ? u0[1] : (i00 == 2) ? u0[2] : u0[3];
    const float ub0 = (i01 == 0) ? u0[0] : (i01 == 1) ? u0[1] : (i01 == 2) ? u0[2] : u0[3];
    const float ua1 = (i10 == 0) ? u1[0] : (i10 == 1) ? u1[1] : (i10 == 2) ? u1[2] : u1[3];
    const float ub1 = (i11 == 0) ? u1[0] : (i11 == 1) ? u1[1] : (i11 == 2) ? u1[2] : u1[3];
    const float d0 = ua0 + ub0 + 1e-20f * ps0;   // == (p0+p1+1e-20)*ps0 scale-free
    const float d1 = ua1 + ub1 + 1e-20f * ps1;
    const float w0a = ua0 / d0, w0b = ub0 / d0;
    const float w1a = ua1 / d1, w1b = ub1 / d1;

    if (lane == 0) {
      const int t = t0 + i;
      float4 idx4 = {(float)i00, (float)i01, (float)i10, (float)i11};
      float4 wt4  = {w0a, w0b, w1a, w1b};
      *(float4*)(out + 2 * t) = idx4;
      *(float4*)(out + 2 * TT + 2 * t) = wt4;
    }
    xA0 = nA0; xB0 = nB0; xA1 = nA1; xB1 = nB1;
  }

  // deterministic block-level combine of aux partials (no atomics)
  __shared__ float part[4][8];
  if (lane == 0) {
#pragma unroll
    for (int e = 0; e < NE; ++e) { part[wave][e] = ssum[e]; part[wave][4 + e] = cnt[e]; }
  }
  __syncthreads();
  if (threadIdx.x < 8) {
    float s = 0.f;
#pragma unroll
    for (int w2 = 0; w2 < 4; ++w2) s += part[w2][threadIdx.x];
    ws[(size_t)blockIdx.x * 8 + threadIdx.x] = s;  // [0..3]=score sums, [4..7]=counts
  }
}

// Parallel reduction over 1024 block-partials (8 KB) -> aux_loss.
// 256 threads: (batch, val, chunk) each sums 32 blocks; 2-level LDS combine.
__global__ void moe_gate_aux(const float* __restrict__ ws, float* __restrict__ out)
{
  __shared__ float part[8][8][4];  // [batch][val][chunk]
  const int j = threadIdx.x;
  const int bb = j >> 5;           // batch 0..7
  const int v  = (j >> 2) & 7;     // value 0..7 (0..3 score-sum, 4..7 count)
  const int c  = j & 3;            // chunk 0..3
  float s = 0.f;
  const int basev = bb * BPB + c * (BPB / 4);
  for (int k = 0; k < BPB / 4; ++k) s += ws[(size_t)(basev + k) * 8 + v];
  part[bb][v][c] = s;
  __syncthreads();
  if (j < 64) {
    const int b2 = j >> 3, v2 = j & 7;
    part[b2][v2][0] = part[b2][v2][0] + part[b2][v2][1] + part[b2][v2][2] + part[b2][v2][3];
  }
  __syncthreads();
  if (j < 32) {
    const int b2 = j >> 2, e = j & 3;
    double term = ((double)part[b2][4 + e][0] / 4096.0) * ((double)part[b2][e][0] / 8192.0);
    term += __shfl_xor(term, 1, 64);
    term += __shfl_xor(term, 2, 64);
    term += __shfl_xor(term, 4, 64);
    term += __shfl_xor(term, 8, 64);
    term += __shfl_xor(term, 16, 64);
    if (j == 0) out[4 * TT] = (float)(0.1 * term / 8.0);
  }
}

extern "C" void kernel_launch(void* const* d_in, const int* in_sizes, int n_in,
                              void* d_out, int out_size, void* d_ws, size_t ws_size,
                              hipStream_t stream) {
  const float* x = (const float*)d_in[0];   // [8,8192,512] fp32
  const float* w = (const float*)d_in[1];   // [4,512] fp32
  float* out = (float*)d_out;               // idx[131072] | weight[131072] | aux[1]
  float* ws  = (float*)d_ws;                // 1024 * 8 floats = 32 KB

  moe_gate_main<<<NBLK, 256, 0, stream>>>(x, w, out, ws);
  moe_gate_aux<<<1, 256, 0, stream>>>(ws, out);
}

// Round 5
// 57.558 us; speedup vs baseline: 1.7044x; 1.7044x over previous
//
#include <hip/hip_runtime.h>

#define TT 65536          // total tokens = 8 * 8192
#define HDIM 512
#define NE 4
#define SEQL 8192
#define TPB 64            // tokens per block (64 lanes of wave 0)
#define NBLK (TT / TPB)   // 1024 blocks
#define BPB (SEQL / TPB)  // 128 blocks per batch
#define SEGH 128          // H per wave-segment (4 waves x 128 = 512)
#define EPS 1e-3f         // ~1000x the fp32 split-accumulation error bound

// Thread-per-token, H split across the 4 waves of a block.
// Wave w computes partial logits over H[128w..128w+128) for 64 tokens
// (lane = token). Main loop: per-lane sequential float4 reads of the
// lane's own row (each 128B line fetched once, fully used by one lane),
// weights via wave-uniform SGPR loads, fp32 accumulate. NO cross-lane
// ops, NO barriers in the loop — kills the ~800cyc/token serial shuffle
// chain that stalled the wave-per-token design (R3/R4 analysis).
// One LDS combine + topk/softmax in wave 0; per-lane fp64 re-dot for
// near-tie tokens (margin < EPS) keeps np-float64 index ordering exact.
__global__ __launch_bounds__(256) void moe_gate_main(
    const float* __restrict__ x, const float* __restrict__ w,
    float* __restrict__ out, float* __restrict__ ws)
{
  const int tid  = threadIdx.x;
  const int lane = tid & 63;                 // token within block
  const int seg  = tid >> 6;                 // H-segment = wave index
  const int useg = __builtin_amdgcn_readfirstlane(seg);  // force SGPR

  __shared__ float comb[TPB][17];            // [token][e*4+seg] partials, padded

  const int t = blockIdx.x * TPB + lane;     // this thread's token
  const float* xrow = x + (size_t)t * HDIM + useg * SEGH;
  const float* wrow = w + useg * SEGH;       // + e*HDIM, wave-uniform

  float a0 = 0.f, a1 = 0.f, a2 = 0.f, a3 = 0.f;
#pragma unroll 8
  for (int j = 0; j < SEGH / 4; ++j) {
    const float4 xv = *(const float4*)(xrow + 4 * j);
    const float4 w0 = *(const float4*)(wrow + 0 * HDIM + 4 * j);
    const float4 w1 = *(const float4*)(wrow + 1 * HDIM + 4 * j);
    const float4 w2 = *(const float4*)(wrow + 2 * HDIM + 4 * j);
    const float4 w3 = *(const float4*)(wrow + 3 * HDIM + 4 * j);
    a0 = fmaf(xv.x, w0.x, a0); a0 = fmaf(xv.y, w0.y, a0);
    a0 = fmaf(xv.z, w0.z, a0); a0 = fmaf(xv.w, w0.w, a0);
    a1 = fmaf(xv.x, w1.x, a1); a1 = fmaf(xv.y, w1.y, a1);
    a1 = fmaf(xv.z, w1.z, a1); a1 = fmaf(xv.w, w1.w, a1);
    a2 = fmaf(xv.x, w2.x, a2); a2 = fmaf(xv.y, w2.y, a2);
    a2 = fmaf(xv.z, w2.z, a2); a2 = fmaf(xv.w, w2.w, a2);
    a3 = fmaf(xv.x, w3.x, a3); a3 = fmaf(xv.y, w3.y, a3);
    a3 = fmaf(xv.z, w3.z, a3); a3 = fmaf(xv.w, w3.w, a3);
  }

  comb[lane][0 * 4 + seg] = a0;
  comb[lane][1 * 4 + seg] = a1;
  comb[lane][2 * 4 + seg] = a2;
  comb[lane][3 * 4 + seg] = a3;
  __syncthreads();

  if (seg == 0) {
    // join 4 segment-partials per expert, fixed order s0..s3
    float acc[NE];
#pragma unroll
    for (int e = 0; e < NE; ++e) {
      acc[e] = ((comb[lane][e * 4 + 0] + comb[lane][e * 4 + 1])
                + comb[lane][e * 4 + 2]) + comb[lane][e * 4 + 3];
    }

    // per-lane top-1/2/3; strict '>' ascending = lowest-index tie-break
    int i0 = 0; float v0 = acc[0];
#pragma unroll
    for (int e = 1; e < NE; ++e) { if (acc[e] > v0) { v0 = acc[e]; i0 = e; } }
    int i1 = -1; float v1 = -3.4e38f;
#pragma unroll
    for (int e = 0; e < NE; ++e) { if (e != i0 && acc[e] > v1) { v1 = acc[e]; i1 = e; } }
    float v2 = -3.4e38f;
#pragma unroll
    for (int e = 0; e < NE; ++e) { if (e != i0 && e != i1 && acc[e] > v2) v2 = acc[e]; }

    // rare per-lane fp64 re-dot for near-ties (exact np-ordering safety)
    if (((v0 - v1) < EPS) | ((v1 - v2) < EPS)) {
      double d0 = 0.0, d1 = 0.0, d2 = 0.0, d3 = 0.0;
      const float* xr = x + (size_t)t * HDIM;
      for (int h = 0; h < HDIM; h += 4) {
        const float4 xv = *(const float4*)(xr + h);
        const float4 q0 = *(const float4*)(w + 0 * HDIM + h);
        const float4 q1 = *(const float4*)(w + 1 * HDIM + h);
        const float4 q2 = *(const float4*)(w + 2 * HDIM + h);
        const float4 q3 = *(const float4*)(w + 3 * HDIM + h);
        d0 += (double)xv.x * q0.x; d0 += (double)xv.y * q0.y;
        d0 += (double)xv.z * q0.z; d0 += (double)xv.w * q0.w;
        d1 += (double)xv.x * q1.x; d1 += (double)xv.y * q1.y;
        d1 += (double)xv.z * q1.z; d1 += (double)xv.w * q1.w;
        d2 += (double)xv.x * q2.x; d2 += (double)xv.y * q2.y;
        d2 += (double)xv.z * q2.z; d2 += (double)xv.w * q2.w;
        d3 += (double)xv.x * q3.x; d3 += (double)xv.y * q3.y;
        d3 += (double)xv.z * q3.z; d3 += (double)xv.w * q3.w;
      }
      const double dd[NE] = {d0, d1, d2, d3};
      i0 = 0; double u0d = dd[0];
#pragma unroll
      for (int e = 1; e < NE; ++e) { if (dd[e] > u0d) { u0d = dd[e]; i0 = e; } }
      i1 = -1; double u1d = -1.0e300;
#pragma unroll
      for (int e = 0; e < NE; ++e) { if (e != i0 && dd[e] > u1d) { u1d = dd[e]; i1 = e; } }
#pragma unroll
      for (int e = 0; e < NE; ++e) acc[e] = (float)dd[e];
      v0 = (float)u0d;
    }

    // softmax (fp32)
    float u[NE]; float psum = 0.f;
#pragma unroll
    for (int e = 0; e < NE; ++e) { u[e] = __expf(acc[e] - v0); psum += u[e]; }
    const float inv = 1.0f / psum;

    const float ua = (i0 == 0) ? u[0] : (i0 == 1) ? u[1] : (i0 == 2) ? u[2] : u[3];
    const float ub = (i1 == 0) ? u[0] : (i1 == 1) ? u[1] : (i1 == 2) ? u[2] : u[3];
    const float denom = ua + ub + 1e-20f * psum;   // == (p0+p1+1e-20)*psum
    const float wt0 = ua / denom, wt1 = ub / denom;

    float2 idx2 = {(float)i0, (float)i1};
    float2 wt2  = {wt0, wt1};
    *(float2*)(out + 2 * t) = idx2;                // coalesced across lanes
    *(float2*)(out + 2 * TT + 2 * t) = wt2;

    // block aux partials: butterfly-reduce 8 values across the wave
    float r[8];
#pragma unroll
    for (int e = 0; e < NE; ++e) {
      r[e] = u[e] * inv;                                       // score sum
      r[4 + e] = ((e == i0) ? 1.f : 0.f) + ((e == i1) ? 1.f : 0.f);  // count
    }
#pragma unroll
    for (int m = 1; m < 64; m <<= 1) {
#pragma unroll
      for (int k = 0; k < 8; ++k) r[k] += __shfl_xor(r[k], m, 64);
    }
    if (lane == 0) {
#pragma unroll
      for (int k = 0; k < 8; ++k) ws[(size_t)blockIdx.x * 8 + k] = r[k];
    }
  }
}

// Parallel reduction over 1024 block-partials (8 KB) -> aux_loss.
// 256 threads: (batch, val, chunk) each sums 32 blocks; 2-level LDS combine.
__global__ void moe_gate_aux(const float* __restrict__ ws, float* __restrict__ out)
{
  __shared__ float part[8][8][4];  // [batch][val][chunk]
  const int j = threadIdx.x;
  const int bb = j >> 5;           // batch 0..7
  const int v  = (j >> 2) & 7;     // value 0..7 (0..3 score-sum, 4..7 count)
  const int c  = j & 3;            // chunk 0..3
  float s = 0.f;
  const int basev = bb * BPB + c * (BPB / 4);
  for (int k = 0; k < BPB / 4; ++k) s += ws[(size_t)(basev + k) * 8 + v];
  part[bb][v][c] = s;
  __syncthreads();
  if (j < 64) {
    const int b2 = j >> 3, v2 = j & 7;
    part[b2][v2][0] = part[b2][v2][0] + part[b2][v2][1] + part[b2][v2][2] + part[b2][v2][3];
  }
  __syncthreads();
  if (j < 32) {
    const int b2 = j >> 2, e = j & 3;
    double term = ((double)part[b2][4 + e][0] / 4096.0) * ((double)part[b2][e][0] / 8192.0);
    term += __shfl_xor(term, 1, 64);
    term += __shfl_xor(term, 2, 64);
    term += __shfl_xor(term, 4, 64);
    term += __shfl_xor(term, 8, 64);
    term += __shfl_xor(term, 16, 64);
    if (j == 0) out[4 * TT] = (float)(0.1 * term / 8.0);
  }
}

extern "C" void kernel_launch(void* const* d_in, const int* in_sizes, int n_in,
                              void* d_out, int out_size, void* d_ws, size_t ws_size,
                              hipStream_t stream) {
  const float* x = (const float*)d_in[0];   // [8,8192,512] fp32
  const float* w = (const float*)d_in[1];   // [4,512] fp32
  float* out = (float*)d_out;               // idx[131072] | weight[131072] | aux[1]
  float* ws  = (float*)d_ws;                // 1024 * 8 floats = 32 KB

  moe_gate_main<<<NBLK, 256, 0, stream>>>(x, w, out, ws);
  moe_gate_aux<<<1, 256, 0, stream>>>(ws, out);
}

// Round 6
// 48.819 us; speedup vs baseline: 2.0095x; 1.1790x over previous
//
#include <hip/hip_runtime.h>

#define TT 65536          // total tokens = 8 * 8192
#define HDIM 512
#define NE 4
#define SEQL 8192
#define TPB 64            // tokens per block
#define NBLK (TT / TPB)   // 1024 blocks
#define BPB (SEQL / TPB)  // 128 blocks per batch
#define CH 64             // chunk size in floats
#define NCH (HDIM / CH)   // 8 chunks
#define ROWF4 17          // 16 float4 + 1 pad float4 per staged row (bank spread)
#define EPS 1e-3f         // ~30x the fp32 512-len dot error bound

// Transpose-through-LDS, expert-per-wave.
//  - 256 threads / 64 tokens per block. x staged to LDS in 64-float chunks,
//    COALESCED global float4 loads (R5's per-lane row reads serialized in
//    TA/L1: 64 lines per instruction -> latency-bound at 12% HBM).
//  - wave w = expert w, lane = token: reads staged rows via the LDS crossbar
//    (padded stride 68 dw -> b128 floor), weights via wave-uniform s_loads.
//    ONE fp32 accumulator per thread; zero cross-lane ops in the main loop
//    (R2/R3: the 7-deep shuffle chain was the stall; R4: spills kill).
//  - wave 0 finishes: 4 b32 LDS gather, per-lane topk/softmax/stores, aux
//    butterfly. Rare per-lane fp64 re-dot (margin < EPS) keeps the np
//    float64 top-k ordering exact.
__global__ __launch_bounds__(256) void moe_gate_main(
    const float* __restrict__ x, const float* __restrict__ w,
    float* __restrict__ out, float* __restrict__ ws)
{
  const int tid  = threadIdx.x;
  const int lane = tid & 63;
  const int wv   = tid >> 6;
  const int e    = __builtin_amdgcn_readfirstlane(wv);   // SGPR expert id

  __shared__ float4 sx[TPB * ROWF4];   // 64 rows x 17 float4 = 17.4 KB
  __shared__ float comb[NE][TPB];      // logit gather, 1 KB

  const int t0 = blockIdx.x * TPB;
  const float4* x4 = (const float4*)x;       // token row = 128 float4
  const float* wrow = w + e * HDIM;          // wave-uniform base

  const int srow = tid >> 4;   // staging row 0..15 (+16k)
  const int scol = tid & 15;   // staging float4-col within chunk

  float a = 0.f;               // logit(token=lane, expert=e)

  // prefetch chunk 0 (4 coalesced float4 per thread)
  float4 pf0, pf1, pf2, pf3;
  {
    const size_t rb = (size_t)t0 * (HDIM / 4) + scol;
    pf0 = x4[rb + (size_t)(srow +  0) * (HDIM / 4)];
    pf1 = x4[rb + (size_t)(srow + 16) * (HDIM / 4)];
    pf2 = x4[rb + (size_t)(srow + 32) * (HDIM / 4)];
    pf3 = x4[rb + (size_t)(srow + 48) * (HDIM / 4)];
  }

  for (int c = 0; c < NCH; ++c) {
    // write staged chunk (prev compute finished at end-of-loop barrier)
    sx[(srow +  0) * ROWF4 + scol] = pf0;
    sx[(srow + 16) * ROWF4 + scol] = pf1;
    sx[(srow + 32) * ROWF4 + scol] = pf2;
    sx[(srow + 48) * ROWF4 + scol] = pf3;
    // issue next chunk's loads early (latency hides under compute below)
    if (c + 1 < NCH) {
      const size_t rb = (size_t)t0 * (HDIM / 4) + (size_t)(c + 1) * (CH / 4) + scol;
      pf0 = x4[rb + (size_t)(srow +  0) * (HDIM / 4)];
      pf1 = x4[rb + (size_t)(srow + 16) * (HDIM / 4)];
      pf2 = x4[rb + (size_t)(srow + 32) * (HDIM / 4)];
      pf3 = x4[rb + (size_t)(srow + 48) * (HDIM / 4)];
    }
    __syncthreads();
    // compute: lane's token row x wave's expert row (s_load weights)
    const float* wc = wrow + c * CH;
#pragma unroll
    for (int j = 0; j < CH / 4; ++j) {
      const float4 xv = sx[lane * ROWF4 + j];
      const float4 qv = *(const float4*)(wc + 4 * j);
      a = fmaf(xv.x, qv.x, a);
      a = fmaf(xv.y, qv.y, a);
      a = fmaf(xv.z, qv.z, a);
      a = fmaf(xv.w, qv.w, a);
    }
    __syncthreads();
  }

  comb[e][lane] = a;
  __syncthreads();

  if (wv == 0) {
    const int t = t0 + lane;
    float acc[NE] = {comb[0][lane], comb[1][lane], comb[2][lane], comb[3][lane]};

    // per-lane top-1/2/3; strict '>' ascending = lowest-index tie-break
    int i0 = 0; float v0 = acc[0];
#pragma unroll
    for (int k = 1; k < NE; ++k) { if (acc[k] > v0) { v0 = acc[k]; i0 = k; } }
    int i1 = -1; float v1 = -3.4e38f;
#pragma unroll
    for (int k = 0; k < NE; ++k) { if (k != i0 && acc[k] > v1) { v1 = acc[k]; i1 = k; } }
    float v2 = -3.4e38f;
#pragma unroll
    for (int k = 0; k < NE; ++k) { if (k != i0 && k != i1 && acc[k] > v2) v2 = acc[k]; }

    // rare per-lane fp64 re-dot for near-ties (exact np-ordering safety)
    if (((v0 - v1) < EPS) | ((v1 - v2) < EPS)) {
      double d0 = 0.0, d1 = 0.0, d2 = 0.0, d3 = 0.0;
      const float* xr = x + (size_t)t * HDIM;
      for (int h = 0; h < HDIM; h += 4) {
        const float4 xv = *(const float4*)(xr + h);
        const float4 q0 = *(const float4*)(w + 0 * HDIM + h);
        const float4 q1 = *(const float4*)(w + 1 * HDIM + h);
        const float4 q2 = *(const float4*)(w + 2 * HDIM + h);
        const float4 q3 = *(const float4*)(w + 3 * HDIM + h);
        d0 += (double)xv.x * q0.x; d0 += (double)xv.y * q0.y;
        d0 += (double)xv.z * q0.z; d0 += (double)xv.w * q0.w;
        d1 += (double)xv.x * q1.x; d1 += (double)xv.y * q1.y;
        d1 += (double)xv.z * q1.z; d1 += (double)xv.w * q1.w;
        d2 += (double)xv.x * q2.x; d2 += (double)xv.y * q2.y;
        d2 += (double)xv.z * q2.z; d2 += (double)xv.w * q2.w;
        d3 += (double)xv.x * q3.x; d3 += (double)xv.y * q3.y;
        d3 += (double)xv.z * q3.z; d3 += (double)xv.w * q3.w;
      }
      const double dd[NE] = {d0, d1, d2, d3};
      i0 = 0; double u0d = dd[0];
#pragma unroll
      for (int k = 1; k < NE; ++k) { if (dd[k] > u0d) { u0d = dd[k]; i0 = k; } }
      i1 = -1; double u1d = -1.0e300;
#pragma unroll
      for (int k = 0; k < NE; ++k) { if (k != i0 && dd[k] > u1d) { u1d = dd[k]; i1 = k; } }
#pragma unroll
      for (int k = 0; k < NE; ++k) acc[k] = (float)dd[k];
      v0 = (float)u0d;
    }

    // softmax (fp32)
    float u[NE]; float psum = 0.f;
#pragma unroll
    for (int k = 0; k < NE; ++k) { u[k] = __expf(acc[k] - v0); psum += u[k]; }
    const float inv = 1.0f / psum;

    const float ua = (i0 == 0) ? u[0] : (i0 == 1) ? u[1] : (i0 == 2) ? u[2] : u[3];
    const float ub = (i1 == 0) ? u[0] : (i1 == 1) ? u[1] : (i1 == 2) ? u[2] : u[3];
    const float denom = ua + ub + 1e-20f * psum;   // == (p0+p1+1e-20)*psum
    const float wt0 = ua / denom, wt1 = ub / denom;

    float2 idx2 = {(float)i0, (float)i1};
    float2 wt2  = {wt0, wt1};
    *(float2*)(out + 2 * t) = idx2;               // 512B coalesced per wave
    *(float2*)(out + 2 * TT + 2 * t) = wt2;

    // aux partials: butterfly-reduce 8 values across the wave, once per block
    float r[8];
#pragma unroll
    for (int k = 0; k < NE; ++k) {
      r[k] = u[k] * inv;                                          // score sum
      r[4 + k] = ((k == i0) ? 1.f : 0.f) + ((k == i1) ? 1.f : 0.f);  // count
    }
#pragma unroll
    for (int m = 1; m < 64; m <<= 1) {
#pragma unroll
      for (int k = 0; k < 8; ++k) r[k] += __shfl_xor(r[k], m, 64);
    }
    if (lane == 0) {
#pragma unroll
      for (int k = 0; k < 8; ++k) ws[(size_t)blockIdx.x * 8 + k] = r[k];
    }
  }
}

// Parallel reduction over 1024 block-partials (8 KB) -> aux_loss.
__global__ void moe_gate_aux(const float* __restrict__ ws, float* __restrict__ out)
{
  __shared__ float part[8][8][4];  // [batch][val][chunk]
  const int j = threadIdx.x;
  const int bb = j >> 5;           // batch 0..7
  const int v  = (j >> 2) & 7;     // value 0..7 (0..3 score-sum, 4..7 count)
  const int c  = j & 3;            // chunk 0..3
  float s = 0.f;
  const int basev = bb * BPB + c * (BPB / 4);
  for (int k = 0; k < BPB / 4; ++k) s += ws[(size_t)(basev + k) * 8 + v];
  part[bb][v][c] = s;
  __syncthreads();
  if (j < 64) {
    const int b2 = j >> 3, v2 = j & 7;
    part[b2][v2][0] = part[b2][v2][0] + part[b2][v2][1] + part[b2][v2][2] + part[b2][v2][3];
  }
  __syncthreads();
  if (j < 32) {
    const int b2 = j >> 2, e = j & 3;
    double term = ((double)part[b2][4 + e][0] / 4096.0) * ((double)part[b2][e][0] / 8192.0);
    term += __shfl_xor(term, 1, 64);
    term += __shfl_xor(term, 2, 64);
    term += __shfl_xor(term, 4, 64);
    term += __shfl_xor(term, 8, 64);
    term += __shfl_xor(term, 16, 64);
    if (j == 0) out[4 * TT] = (float)(0.1 * term / 8.0);
  }
}

extern "C" void kernel_launch(void* const* d_in, const int* in_sizes, int n_in,
                              void* d_out, int out_size, void* d_ws, size_t ws_size,
                              hipStream_t stream) {
  const float* x = (const float*)d_in[0];   // [8,8192,512] fp32
  const float* w = (const float*)d_in[1];   // [4,512] fp32
  float* out = (float*)d_out;               // idx[131072] | weight[131072] | aux[1]
  float* ws  = (float*)d_ws;                // 1024 * 8 floats = 32 KB

  moe_gate_main<<<NBLK, 256, 0, stream>>>(x, w, out, ws);
  moe_gate_aux<<<1, 256, 0, stream>>>(ws, out);
}